// Round 3
// baseline (228.578 us; speedup 1.0000x reference)
//
#include <hip/hip_runtime.h>
#include <math.h>

// Problem constants (from reference setup_inputs): B=32, H=W=1024.
constexpr int B = 32;
constexpr int H = 1024;
constexpr int W = 1024;
constexpr int NBLK = 2048;      // total blocks; each handles 16 global rows
constexpr int ROWS = (B * H) / NBLK;  // 16 rows per block, striped across batches
constexpr int NTHREADS = 256;   // 256 threads * float4 = 1024 floats = one row

// Single-pass fused kernel.
// Global row r = blk + NBLK*i (i<16): batch b = r>>10, image row y = r&1023.
// Striping means each block touches 16 different batches -> balanced work.
// Per-row contributions are scaled by the batch's analytic 1/cnt so partials
// are batch-agnostic; the LAST block (int-atomic counter, deterministic) sums
// the 2048 partials in fixed order and writes the scalar result.
//
// ws layout: [0..NBLK) float partials, then one uint counter at ws[NBLK]
// (counter is zeroed each replay by a hipMemsetAsync node in kernel_launch).
__global__ __launch_bounds__(NTHREADS)
void fused_kernel(const float* __restrict__ pred,
                  const float* __restrict__ bboxes,
                  float* __restrict__ ws,
                  float* __restrict__ out) {
    const int blk = blockIdx.x;
    const int tid = threadIdx.x;

    float acc = 0.0f;
    for (int i = 0; i < ROWS; ++i) {
        const int r = blk + NBLK * i;
        const int b = r >> 10;
        const int y = r & (H - 1);

        // bbox -> integer pixel bounds, exactly matching the reference.
        const int x1 = max((int)floorf(bboxes[b * 4 + 0] * (float)W), 0);
        const int y1 = max((int)floorf(bboxes[b * 4 + 1] * (float)H), 0);
        const int x2 = min((int)floorf(bboxes[b * 4 + 2] * (float)W), W);
        const int y2 = min((int)floorf(bboxes[b * 4 + 3] * (float)H), H);

        const float area = (float)max(0, y2 - y1) * (float)max(0, x2 - x1);
        const float cnt  = (float)(H * W) - area;
        const float inv  = (cnt > 0.0f) ? (1.0f / fmaxf(cnt, 1.0f)) : 0.0f;

        const bool yin = (y >= y1) && (y < y2);
        int c4;
        if (yin) {
            const int nL   = (x1 + 3) >> 2;    // left-segment float4 count
            const int rS   = x2 >> 2;          // right-segment first float4
            const int nAct = nL + (256 - rS);  // active threads this row
            if (tid < nL)        c4 = tid;
            else if (tid < nAct) c4 = rS + (tid - nL);
            else continue;                     // idle waves skip via execz
        } else {
            c4 = tid;
        }

        const float4 v = *reinterpret_cast<const float4*>(
            pred + (size_t)b * H * W + (size_t)y * W + (c4 << 2));
        const float pv[4] = {v.x, v.y, v.z, v.w};
        float racc = 0.0f;
#pragma unroll
        for (int j = 0; j < 4; ++j) {
            const int x = (c4 << 2) + j;
            const bool inside = yin && (x >= x1) && (x < x2);
            if (!inside) racc -= __logf(1.0f - pv[j] + 1e-7f);
        }
        acc += racc * inv;
    }

    // block reduction: wave shfl, then LDS across 4 waves
    for (int off = 32; off > 0; off >>= 1)
        acc += __shfl_down(acc, off, 64);
    __shared__ float s[NTHREADS / 64];
    const int wave = tid >> 6;
    if ((tid & 63) == 0) s[wave] = acc;
    __syncthreads();
    if (tid == 0)
        ws[blk] = s[0] + s[1] + s[2] + s[3];

    // --- single-pass completion: last block reduces all partials ---
    __threadfence();  // release: make this block's partial visible device-wide
    __shared__ unsigned last;
    if (tid == 0) {
        unsigned* counter = (unsigned*)(ws + NBLK);
        last = atomicAdd(counter, 1u);
    }
    __syncthreads();
    if (last == (unsigned)(NBLK - 1)) {
        __threadfence();  // acquire: see all other blocks' partials
        float t = 0.0f;
        const float* p = ws + (size_t)tid * (NBLK / NTHREADS);
#pragma unroll
        for (int i = 0; i < NBLK / NTHREADS; ++i) t += p[i];
        for (int off = 32; off > 0; off >>= 1)
            t += __shfl_down(t, off, 64);
        __shared__ float s2[NTHREADS / 64];
        if ((tid & 63) == 0) s2[wave] = t;
        __syncthreads();
        if (tid == 0)
            out[0] = (s2[0] + s2[1] + s2[2] + s2[3]) * (1.0f / (float)B);
    }
}

extern "C" void kernel_launch(void* const* d_in, const int* in_sizes, int n_in,
                              void* d_out, int out_size, void* d_ws, size_t ws_size,
                              hipStream_t stream) {
    const float* pred   = (const float*)d_in[0];  // (B,1,H,W) f32
    const float* bboxes = (const float*)d_in[1];  // (B,4) f32
    float* out = (float*)d_out;                   // scalar f32
    float* ws  = (float*)d_ws;                    // NBLK partials + 1 counter

    // zero the completion counter (memset node -> runs every graph replay)
    hipMemsetAsync((char*)d_ws + (size_t)NBLK * sizeof(float), 0,
                   sizeof(unsigned), stream);
    fused_kernel<<<NBLK, NTHREADS, 0, stream>>>(pred, bboxes, ws, out);
}

// Round 4
// 30.085 us; speedup vs baseline: 7.5977x; 7.5977x over previous
//
#include <hip/hip_runtime.h>
#include <math.h>

// Problem constants (from reference setup_inputs): B=32, H=W=1024.
constexpr int B = 32;
constexpr int H = 1024;
constexpr int W = 1024;
constexpr int NBLK = 2048;            // total blocks
constexpr int ROWS = (B * H) / NBLK;  // 16 global rows per block, striped
constexpr int NTHREADS = 256;         // 256 threads * float4 = one 1024-px row

// Kernel 1: partial sums of (1/cnt_b) * -log(1 - p + eps) over outside pixels.
// Global row r = blk + NBLK*i (i<16): batch b = r>>10, image row y = r&1023.
// Striping across batches balances per-block work (no slow-batch tail).
// For rows inside [y1,y2): loads are compacted to the outside column ranges;
// fully-idle waves skip via execz. No fences/atomics — kernel 2 finishes.
__global__ __launch_bounds__(NTHREADS)
void partial_kernel(const float* __restrict__ pred,
                    const float* __restrict__ bboxes,
                    float* __restrict__ ws) {
    const int blk = blockIdx.x;
    const int tid = threadIdx.x;

    float acc = 0.0f;
    for (int i = 0; i < ROWS; ++i) {
        const int r = blk + NBLK * i;
        const int b = r >> 10;
        const int y = r & (H - 1);

        // bbox -> integer pixel bounds, exactly matching the reference.
        const int x1 = max((int)floorf(bboxes[b * 4 + 0] * (float)W), 0);
        const int y1 = max((int)floorf(bboxes[b * 4 + 1] * (float)H), 0);
        const int x2 = min((int)floorf(bboxes[b * 4 + 2] * (float)W), W);
        const int y2 = min((int)floorf(bboxes[b * 4 + 3] * (float)H), H);

        const float area = (float)max(0, y2 - y1) * (float)max(0, x2 - x1);
        const float cnt  = (float)(H * W) - area;
        const float inv  = (cnt > 0.0f) ? (1.0f / fmaxf(cnt, 1.0f)) : 0.0f;

        const bool yin = (y >= y1) && (y < y2);
        int c4;
        if (yin) {
            const int nL   = (x1 + 3) >> 2;    // left-segment float4 count
            const int rS   = x2 >> 2;          // right-segment first float4
            const int nAct = nL + (256 - rS);  // active threads this row
            if (tid < nL)        c4 = tid;
            else if (tid < nAct) c4 = rS + (tid - nL);
            else continue;                     // idle waves skip via execz
        } else {
            c4 = tid;
        }

        const float4 v = *reinterpret_cast<const float4*>(
            pred + (size_t)b * H * W + (size_t)y * W + (c4 << 2));
        const float pv[4] = {v.x, v.y, v.z, v.w};
        float racc = 0.0f;
#pragma unroll
        for (int j = 0; j < 4; ++j) {
            const int x = (c4 << 2) + j;
            const bool inside = yin && (x >= x1) && (x < x2);
            if (!inside) racc -= __logf(1.0f - pv[j] + 1e-7f);
        }
        acc += racc * inv;
    }

    // block reduction: wave shfl, then LDS across 4 waves
    for (int off = 32; off > 0; off >>= 1)
        acc += __shfl_down(acc, off, 64);
    __shared__ float s[NTHREADS / 64];
    const int wave = tid >> 6;
    if ((tid & 63) == 0) s[wave] = acc;
    __syncthreads();
    if (tid == 0)
        ws[blk] = s[0] + s[1] + s[2] + s[3];
}

// Kernel 2: one block of 256 threads sums the 2048 partials in a FIXED order
// (deterministic across replays) and writes the scalar mean.
__global__ __launch_bounds__(NTHREADS)
void finalize_kernel(const float* __restrict__ ws, float* __restrict__ out) {
    const int tid = threadIdx.x;
    float t = 0.0f;
    const float* p = ws + (size_t)tid * (NBLK / NTHREADS);
#pragma unroll
    for (int i = 0; i < NBLK / NTHREADS; ++i) t += p[i];
    for (int off = 32; off > 0; off >>= 1)
        t += __shfl_down(t, off, 64);
    __shared__ float s[NTHREADS / 64];
    const int wave = tid >> 6;
    if ((tid & 63) == 0) s[wave] = t;
    __syncthreads();
    if (tid == 0)
        out[0] = (s[0] + s[1] + s[2] + s[3]) * (1.0f / (float)B);
}

extern "C" void kernel_launch(void* const* d_in, const int* in_sizes, int n_in,
                              void* d_out, int out_size, void* d_ws, size_t ws_size,
                              hipStream_t stream) {
    const float* pred   = (const float*)d_in[0];  // (B,1,H,W) f32
    const float* bboxes = (const float*)d_in[1];  // (B,4) f32
    float* out = (float*)d_out;                   // scalar f32
    float* ws  = (float*)d_ws;                    // NBLK float partials (8 KB)

    partial_kernel<<<NBLK, NTHREADS, 0, stream>>>(pred, bboxes, ws);
    finalize_kernel<<<1, NTHREADS, 0, stream>>>(ws, out);
}

// Round 5
// 28.715 us; speedup vs baseline: 7.9602x; 1.0477x over previous
//
#include <hip/hip_runtime.h>
#include <math.h>

// Problem constants (from reference setup_inputs): B=32, H=W=1024.
constexpr int B = 32;
constexpr int H = 1024;
constexpr int W = 1024;
constexpr int NBLK = 2048;            // total blocks
constexpr int ROWS = (B * H) / NBLK;  // 16 rows per block, striped over batches
constexpr int NTHREADS = 256;         // 256 threads * float4 = one 1024-px row

// Kernel 1: partial sums of (1/cnt_b) * -log(1 - p + eps) over outside pixels.
// Row mapping: global row r = blk + NBLK*i  ->  b = (blk>>10) + 2*i,
// y = blk & 1023 (NOTE: y is the SAME for all 16 iterations; only the batch
// changes). Striping across batches balances per-block work.
// All 32 batches' bounds (+ precise 1/cnt) are computed ONCE per block into
// LDS by the first wave; the unrolled main loop reads broadcast LDS values,
// so the pixel-load address path has no global-load or division dependency.
__global__ __launch_bounds__(NTHREADS)
void partial_kernel(const float* __restrict__ pred,
                    const float* __restrict__ bboxes,
                    float* __restrict__ ws) {
    const int blk   = blockIdx.x;
    const int tid   = threadIdx.x;
    const int blkHi = blk >> 10;      // 0 or 1
    const int y     = blk & (H - 1);  // row index shared by all iterations

    __shared__ int   s_x1[B], s_x2[B], s_y1[B], s_y2[B];
    __shared__ int   s_nL[B], s_rS[B], s_nAct[B];
    __shared__ float s_inv[B];
    if (tid < B) {
        const int b = tid;
        // bbox -> integer pixel bounds, exactly matching the reference.
        const int x1 = max((int)floorf(bboxes[b * 4 + 0] * (float)W), 0);
        const int y1 = max((int)floorf(bboxes[b * 4 + 1] * (float)H), 0);
        const int x2 = min((int)floorf(bboxes[b * 4 + 2] * (float)W), W);
        const int y2 = min((int)floorf(bboxes[b * 4 + 3] * (float)H), H);
        const float area = (float)max(0, y2 - y1) * (float)max(0, x2 - x1);
        const float cnt  = (float)(H * W) - area;
        const int nL = (x1 + 3) >> 2;      // left-segment float4 count
        const int rS = x2 >> 2;            // right-segment first float4
        s_x1[b] = x1;  s_x2[b] = x2;  s_y1[b] = y1;  s_y2[b] = y2;
        s_nL[b] = nL;  s_rS[b] = rS;  s_nAct[b] = nL + (256 - rS);
        s_inv[b] = (cnt > 0.0f) ? (1.0f / fmaxf(cnt, 1.0f)) : 0.0f;
    }
    __syncthreads();

    float acc = 0.0f;
#pragma unroll
    for (int i = 0; i < ROWS; ++i) {
        const int b = blkHi + 2 * i;
        const bool yin = (y >= s_y1[b]) && (y < s_y2[b]);
        int c4;
        if (yin) {
            if (tid < s_nL[b])        c4 = tid;
            else if (tid < s_nAct[b]) c4 = s_rS[b] + (tid - s_nL[b]);
            else continue;                 // idle waves skip via execz
        } else {
            c4 = tid;
        }

        const float4 v = *reinterpret_cast<const float4*>(
            pred + ((size_t)b << 20) + ((size_t)y << 10) + (c4 << 2));
        const float pv[4] = {v.x, v.y, v.z, v.w};
        float racc = 0.0f;
#pragma unroll
        for (int j = 0; j < 4; ++j) {
            const int x = (c4 << 2) + j;
            const bool inside = yin && (x >= s_x1[b]) && (x < s_x2[b]);
            if (!inside) racc -= __logf(1.0f - pv[j] + 1e-7f);
        }
        acc += racc * s_inv[b];
    }

    // block reduction: wave shfl, then LDS across 4 waves
    for (int off = 32; off > 0; off >>= 1)
        acc += __shfl_down(acc, off, 64);
    __shared__ float s[NTHREADS / 64];
    const int wave = tid >> 6;
    if ((tid & 63) == 0) s[wave] = acc;
    __syncthreads();
    if (tid == 0)
        ws[blk] = s[0] + s[1] + s[2] + s[3];
}

// Kernel 2: one block of 256 threads sums the 2048 partials in a FIXED order
// (deterministic across replays) and writes the scalar mean.
__global__ __launch_bounds__(NTHREADS)
void finalize_kernel(const float* __restrict__ ws, float* __restrict__ out) {
    const int tid = threadIdx.x;
    float t = 0.0f;
    const float* p = ws + (size_t)tid * (NBLK / NTHREADS);
#pragma unroll
    for (int i = 0; i < NBLK / NTHREADS; ++i) t += p[i];
    for (int off = 32; off > 0; off >>= 1)
        t += __shfl_down(t, off, 64);
    __shared__ float s[NTHREADS / 64];
    const int wave = tid >> 6;
    if ((tid & 63) == 0) s[wave] = t;
    __syncthreads();
    if (tid == 0)
        out[0] = (s[0] + s[1] + s[2] + s[3]) * (1.0f / (float)B);
}

extern "C" void kernel_launch(void* const* d_in, const int* in_sizes, int n_in,
                              void* d_out, int out_size, void* d_ws, size_t ws_size,
                              hipStream_t stream) {
    const float* pred   = (const float*)d_in[0];  // (B,1,H,W) f32
    const float* bboxes = (const float*)d_in[1];  // (B,4) f32
    float* out = (float*)d_out;                   // scalar f32
    float* ws  = (float*)d_ws;                    // NBLK float partials (8 KB)

    partial_kernel<<<NBLK, NTHREADS, 0, stream>>>(pred, bboxes, ws);
    finalize_kernel<<<1, NTHREADS, 0, stream>>>(ws, out);
}

// Round 6
// 24.838 us; speedup vs baseline: 9.2029x; 1.1561x over previous
//
#include <hip/hip_runtime.h>
#include <math.h>

// Problem constants (from reference setup_inputs): B=32, H=W=1024.
constexpr int B = 32;
constexpr int H = 1024;
constexpr int W = 1024;
constexpr int BPB  = 128;             // blocks per batch
constexpr int NBLK = B * BPB;         // 4096 blocks (2x CU-resident slots)
constexpr int RPB  = H / BPB;         // 8 contiguous rows per block
constexpr int NTHREADS = 256;         // 256 threads * float4 = one 1024-px row

// Kernel 1: partial sums of (1/cnt_b) * -log(1 - p + eps) over outside pixels.
// Block g: batch b = g & 31 (interleaved so the resident set spans all batches
// -> scheduler backfill balances uneven bbox work), rows y0..y0+7 where
// y0 = (g >> 5) * 8 (contiguous 32 KB footprint, bounds wave-uniform in SGPRs).
// Inside-y rows: loads compacted to outside column segments; fully-idle
// threads skip. No atomics, no fences - kernel 2 completes the reduction.
__global__ __launch_bounds__(NTHREADS)
void partial_kernel(const float* __restrict__ pred,
                    const float* __restrict__ bboxes,
                    float* __restrict__ ws) {
    const int g   = blockIdx.x;
    const int b   = g & (B - 1);          // batch (wave-uniform, scalar)
    const int y0  = (g >> 5) * RPB;       // first row
    const int tid = threadIdx.x;

    // bbox -> integer pixel bounds, exactly matching the reference (scalar).
    const int x1 = max((int)floorf(bboxes[b * 4 + 0] * (float)W), 0);
    const int y1 = max((int)floorf(bboxes[b * 4 + 1] * (float)H), 0);
    const int x2 = min((int)floorf(bboxes[b * 4 + 2] * (float)W), W);
    const int y2 = min((int)floorf(bboxes[b * 4 + 3] * (float)H), H);

    const float area = (float)max(0, y2 - y1) * (float)max(0, x2 - x1);
    const float cnt  = (float)(H * W) - area;
    const float inv  = (cnt > 0.0f) ? (1.0f / fmaxf(cnt, 1.0f)) : 0.0f;

    const int nL   = (x1 + 3) >> 2;    // left-segment float4 count
    const int rS   = x2 >> 2;          // right-segment first float4
    const int nAct = nL + (256 - rS);  // active threads on inside-y rows

    const float* base = pred + ((size_t)b << 20);

    float acc = 0.0f;
#pragma unroll
    for (int j = 0; j < RPB; ++j) {
        const int y = y0 + j;
        const bool yin = (y >= y1) && (y < y2);   // scalar per row
        int c4;
        if (yin) {
            if (tid < nL)        c4 = tid;
            else if (tid < nAct) c4 = rS + (tid - nL);
            else continue;                        // idle threads skip
        } else {
            c4 = tid;
        }

        const float4 v = *reinterpret_cast<const float4*>(
            base + ((size_t)y << 10) + (c4 << 2));
        const float pv[4] = {v.x, v.y, v.z, v.w};
#pragma unroll
        for (int k = 0; k < 4; ++k) {
            const int x = (c4 << 2) + k;
            const bool inside = yin && (x >= x1) && (x < x2);
            if (!inside) acc -= __logf(1.0f - pv[k] + 1e-7f);
        }
    }
    acc *= inv;   // batch-agnostic partial (pre-normalized)

    // block reduction: wave shfl, then LDS across 4 waves
    for (int off = 32; off > 0; off >>= 1)
        acc += __shfl_down(acc, off, 64);
    __shared__ float s[NTHREADS / 64];
    const int wave = tid >> 6;
    if ((tid & 63) == 0) s[wave] = acc;
    __syncthreads();
    if (tid == 0)
        ws[g] = s[0] + s[1] + s[2] + s[3];
}

// Kernel 2: one block of 256 threads sums the 4096 partials in a FIXED order
// (deterministic across replays) and writes the scalar mean.
__global__ __launch_bounds__(NTHREADS)
void finalize_kernel(const float* __restrict__ ws, float* __restrict__ out) {
    const int tid = threadIdx.x;
    float t = 0.0f;
    const float* p = ws + (size_t)tid * (NBLK / NTHREADS);
#pragma unroll
    for (int i = 0; i < NBLK / NTHREADS; ++i) t += p[i];
    for (int off = 32; off > 0; off >>= 1)
        t += __shfl_down(t, off, 64);
    __shared__ float s[NTHREADS / 64];
    const int wave = tid >> 6;
    if ((tid & 63) == 0) s[wave] = t;
    __syncthreads();
    if (tid == 0)
        out[0] = (s[0] + s[1] + s[2] + s[3]) * (1.0f / (float)B);
}

extern "C" void kernel_launch(void* const* d_in, const int* in_sizes, int n_in,
                              void* d_out, int out_size, void* d_ws, size_t ws_size,
                              hipStream_t stream) {
    const float* pred   = (const float*)d_in[0];  // (B,1,H,W) f32
    const float* bboxes = (const float*)d_in[1];  // (B,4) f32
    float* out = (float*)d_out;                   // scalar f32
    float* ws  = (float*)d_ws;                    // NBLK float partials (16 KB)

    partial_kernel<<<NBLK, NTHREADS, 0, stream>>>(pred, bboxes, ws);
    finalize_kernel<<<1, NTHREADS, 0, stream>>>(ws, out);
}

// Round 7
// 21.227 us; speedup vs baseline: 10.7681x; 1.1701x over previous
//
#include <hip/hip_runtime.h>
#include <math.h>

// Problem constants (from reference setup_inputs): B=32, H=W=1024.
constexpr int B = 32;
constexpr int H = 1024;
constexpr int W = 1024;
constexpr int BPB  = 64;              // blocks per batch; also the row stride
constexpr int ROWS = H / BPB;         // 16 rows per block (y = blk + 64*i)
constexpr int NBLK = B * BPB;         // 2048 blocks (exactly CU-resident)
constexpr int NTHREADS = 256;         // 256 threads * float4 = one 1024-px row
constexpr int STR = BPB * W;          // floats per i-step (64 rows)

__device__ __forceinline__ float row4(const float4 v) {
    float s = 0.0f;
    s -= __logf(1.0f - v.x + 1e-7f);
    s -= __logf(1.0f - v.y + 1e-7f);
    s -= __logf(1.0f - v.z + 1e-7f);
    s -= __logf(1.0f - v.w + 1e-7f);
    return s;
}
__device__ __forceinline__ float row4w(const float4 v, const float4 w) {
    float s = 0.0f;
    s -= w.x * __logf(1.0f - v.x + 1e-7f);
    s -= w.y * __logf(1.0f - v.y + 1e-7f);
    s -= w.z * __logf(1.0f - v.z + 1e-7f);
    s -= w.w * __logf(1.0f - v.w + 1e-7f);
    return s;
}

// Kernel 1: partial sums of (1/cnt_b) * -log(1 - p + eps) over outside pixels.
// Block g: batch b = g>>6, row set y = (g&63) + 64*i, i<16 (R2's proven
// layout). KEY CHANGE vs all prior rounds: y is monotone in i, so the
// inside-bbox rows are a contiguous interval [iLo,iHi) in i-space. The loop
// is split into three BRANCHLESS tight loops (outside-before / outside-after
// full rows; inside rows with compacted columns + constant per-element
// weights). Loads are manually paired so >=2 are in flight per wave --
// the previous per-iteration scalar branch serialized every load (latency-
// bound at ~1 load in flight).
__global__ __launch_bounds__(NTHREADS)
void partial_kernel(const float* __restrict__ pred,
                    const float* __restrict__ bboxes,
                    float* __restrict__ ws) {
    const int g   = blockIdx.x;
    const int b   = g >> 6;
    const int blk = g & (BPB - 1);
    const int tid = threadIdx.x;

    // bbox -> integer pixel bounds, exactly matching the reference (scalar).
    const int x1 = max((int)floorf(bboxes[b * 4 + 0] * (float)W), 0);
    const int y1 = max((int)floorf(bboxes[b * 4 + 1] * (float)H), 0);
    const int x2 = min((int)floorf(bboxes[b * 4 + 2] * (float)W), W);
    const int y2 = min((int)floorf(bboxes[b * 4 + 3] * (float)H), H);

    const float area = (float)max(0, y2 - y1) * (float)max(0, x2 - x1);
    const float cnt  = (float)(H * W) - area;
    const float inv  = (cnt > 0.0f) ? (1.0f / fmaxf(cnt, 1.0f)) : 0.0f;

    // inside-row interval in i-space: y1 <= blk+64i < y2  (arith-shift = floor)
    const int iLo = min(ROWS, max(0, (y1 - blk + 63) >> 6));
    const int iHi = min(ROWS, max(iLo, (y2 - blk + 63) >> 6));

    const float* base = pred + ((size_t)b << 20) + ((size_t)blk << 10);
    const float* pO   = base + (tid << 2);   // this thread's full-row address

    float acc = 0.0f, acc2 = 0.0f;

    // --- outside rows before the bbox: i in [0, iLo), branchless pairs
    {
        int i = 0;
        for (; i + 2 <= iLo; i += 2) {
            const float4 va = *reinterpret_cast<const float4*>(pO + (size_t)i * STR);
            const float4 vb = *reinterpret_cast<const float4*>(pO + (size_t)(i + 1) * STR);
            acc += row4(va);
            acc2 += row4(vb);
        }
        if (i < iLo)
            acc += row4(*reinterpret_cast<const float4*>(pO + (size_t)i * STR));
    }
    // --- outside rows after the bbox: i in [iHi, ROWS)
    {
        int i = iHi;
        for (; i + 2 <= ROWS; i += 2) {
            const float4 va = *reinterpret_cast<const float4*>(pO + (size_t)i * STR);
            const float4 vb = *reinterpret_cast<const float4*>(pO + (size_t)(i + 1) * STR);
            acc += row4(va);
            acc2 += row4(vb);
        }
        if (i < ROWS)
            acc += row4(*reinterpret_cast<const float4*>(pO + (size_t)i * STR));
    }
    // --- inside rows: compacted columns, constant per-element weights
    {
        const int nL   = (x1 + 3) >> 2;     // left-segment float4 count
        const int rS   = x2 >> 2;           // right-segment first float4
        const int nAct = nL + (256 - rS);   // active threads on inside rows
        if (tid < nAct) {
            const int c4 = (tid < nL) ? tid : (rS + tid - nL);
            const int x0 = c4 << 2;
            const float4 w = make_float4(
                (x0 + 0 >= x1 && x0 + 0 < x2) ? 0.0f : 1.0f,
                (x0 + 1 >= x1 && x0 + 1 < x2) ? 0.0f : 1.0f,
                (x0 + 2 >= x1 && x0 + 2 < x2) ? 0.0f : 1.0f,
                (x0 + 3 >= x1 && x0 + 3 < x2) ? 0.0f : 1.0f);
            const float* pI = base + x0;
            int i = iLo;
            for (; i + 2 <= iHi; i += 2) {
                const float4 va = *reinterpret_cast<const float4*>(pI + (size_t)i * STR);
                const float4 vb = *reinterpret_cast<const float4*>(pI + (size_t)(i + 1) * STR);
                acc += row4w(va, w);
                acc2 += row4w(vb, w);
            }
            if (i < iHi)
                acc += row4w(*reinterpret_cast<const float4*>(pI + (size_t)i * STR), w);
        }
    }

    float t = (acc + acc2) * inv;   // batch-agnostic partial (pre-normalized)

    // block reduction: wave shfl, then LDS across 4 waves
    for (int off = 32; off > 0; off >>= 1)
        t += __shfl_down(t, off, 64);
    __shared__ float s[NTHREADS / 64];
    const int wave = tid >> 6;
    if ((tid & 63) == 0) s[wave] = t;
    __syncthreads();
    if (tid == 0)
        ws[g] = s[0] + s[1] + s[2] + s[3];
}

// Kernel 2: one block of 256 threads sums the 2048 partials in a FIXED order
// (deterministic across replays) and writes the scalar mean.
__global__ __launch_bounds__(NTHREADS)
void finalize_kernel(const float* __restrict__ ws, float* __restrict__ out) {
    const int tid = threadIdx.x;
    float t = 0.0f;
    const float* p = ws + (size_t)tid * (NBLK / NTHREADS);
#pragma unroll
    for (int i = 0; i < NBLK / NTHREADS; ++i) t += p[i];
    for (int off = 32; off > 0; off >>= 1)
        t += __shfl_down(t, off, 64);
    __shared__ float s[NTHREADS / 64];
    const int wave = tid >> 6;
    if ((tid & 63) == 0) s[wave] = t;
    __syncthreads();
    if (tid == 0)
        out[0] = (s[0] + s[1] + s[2] + s[3]) * (1.0f / (float)B);
}

extern "C" void kernel_launch(void* const* d_in, const int* in_sizes, int n_in,
                              void* d_out, int out_size, void* d_ws, size_t ws_size,
                              hipStream_t stream) {
    const float* pred   = (const float*)d_in[0];  // (B,1,H,W) f32
    const float* bboxes = (const float*)d_in[1];  // (B,4) f32
    float* out = (float*)d_out;                   // scalar f32
    float* ws  = (float*)d_ws;                    // NBLK float partials (8 KB)

    partial_kernel<<<NBLK, NTHREADS, 0, stream>>>(pred, bboxes, ws);
    finalize_kernel<<<1, NTHREADS, 0, stream>>>(ws, out);
}